// Round 7
// baseline (122.461 us; speedup 1.0000x reference)
//
#include <hip/hip_runtime.h>
#include <hip/hip_fp16.h>

// GAE reverse affine scan + standardize, software-pipelined streaming version.
// adv_k = delta_k + c_k*adv_{k+1}; delta_k = r_k + g*V_{k+1}*nd_k - V_k; c_k = g*l*nd_k.
// Affine f(x)=D+C*x; compose(left,right) = (Dl+Cl*Dr, Cl*Cr).
// Wave owns a 1024-elem chunk = 4 tiles of 256 (1 float4/lane/stream per tile).
// Pass 1 pipelines tile loads 2-deep with DISJOINT register sets (A/B) so the
// compiler can keep tile t+1's loads in flight across tile t's shuffle scan.
// Pass 1 persists fp16 delta (32 MB) + done bitmask (2 MB); pass 3 reads only those
// (L3-hot) and writes normalized out. ws_size >= 36 MB proven in R6 (half path ran).

#define GAMMA_F 0.99f
#define GL_F 0.9405f            // 0.99*0.95
#define EPS_F 1e-8f

constexpr int NT = 256;          // 4 waves per block
constexpr int TILE = 256;        // elems per wave-tile (64 lanes * 4)
constexpr int TPC = 4;           // tiles per chunk
constexpr int CHUNK = TILE * TPC;   // 1024
constexpr int K2T = 1024;        // k_scan threads

union H4 { __half h[4]; uint2 u2; };

struct TR { float4 rr, vv; int4 dd; float vx; };

__device__ __forceinline__ void load_tile(const float* __restrict__ r,
                                          const float* __restrict__ v,
                                          const int* __restrict__ dn,
                                          int tb, int lane, TR& t) {
    const int e = tb + lane * 4;
    t.rr = *(const float4*)(r + e);
    t.vv = *(const float4*)(v + e);
    t.dd = *(const int4*)(dn + e);
    t.vx = 0.f;
    if (lane == 63) t.vx = v[tb + TILE];   // tile-edge neighbor (v has T+1 elems)
}

// Process one 256-elem tile: delta/cont, persist fp16 delta + mask, wave suffix
// scan, fold tile moments + tile affine into running chunk state. Lane-local
// except shuffles; no LDS, no barriers.
__device__ __forceinline__ void process_tile(const TR& tr, int lane, int ch, int t,
                                             __half* __restrict__ dh,
                                             unsigned long long* __restrict__ dmask,
                                             int tb,
                                             float& KD, float& KC,
                                             float& gA, float& gP, float& gL2,
                                             float& gLP, float& gP2) {
    float vnext = __shfl_down(tr.vv.x, 1);
    if (lane == 63) vnext = tr.vx;
    float va[5] = {tr.vv.x, tr.vv.y, tr.vv.z, tr.vv.w, vnext};
    float rf[4] = {tr.rr.x, tr.rr.y, tr.rr.z, tr.rr.w};
    int   di[4] = {tr.dd.x, tr.dd.y, tr.dd.z, tr.dd.w};
    float d[4], c[4];
    unsigned long long mb[4];
#pragma unroll
    for (int i = 0; i < 4; ++i) {
        float nd = 1.f - (float)di[i];
        d[i] = rf[i] + GAMMA_F * va[i + 1] * nd - va[i];
        c[i] = GL_F * nd;
        mb[i] = __ballot(di[i] != 0);
    }
    // persist fp16 delta (coalesced 8B/lane)
    H4 u;
#pragma unroll
    for (int i = 0; i < 4; ++i) u.h[i] = __float2half(d[i]);
    *(uint2*)(dh + tb + lane * 4) = u.u2;
    // persist mask: lanes 0..3 each store one u64
    unsigned long long mv = mb[0];
    if (lane == 1) mv = mb[1];
    if (lane == 2) mv = mb[2];
    if (lane == 3) mv = mb[3];
    if (lane < 4) dmask[(size_t)ch * 16 + t * 4 + lane] = mv;
    // lane affine + wave suffix scan (A_lane ∘ ... ∘ A_63)
    float D = 0.f, C = 1.f;
#pragma unroll
    for (int i = 3; i >= 0; --i) { D = d[i] + c[i] * D; C *= c[i]; }
#pragma unroll
    for (int off = 1; off < 64; off <<= 1) {
        float tD = __shfl_down(D, off), tC = __shfl_down(C, off);
        if (lane + off < 64) { D = D + C * tD; C = C * tC; }
    }
    float S1D = __shfl_down(D, 1), S1C = __shfl_down(C, 1);
    if (lane == 63) { S1D = 0.f; S1C = 1.f; }
    const float tD0 = __shfl(D, 0), tC0 = __shfl(C, 0);   // tile total
    // lane moments for this tile (entry 0 at tile right edge)
    float x = S1D, P = S1C, A = 0.f, Pp = 0.f, L2 = 0.f, LP = 0.f, P2 = 0.f;
#pragma unroll
    for (int i = 3; i >= 0; --i) {
        x = d[i] + c[i] * x; P *= c[i];
        A += x; Pp += P; L2 += x * x; LP += x * P; P2 += P * P;
    }
    // lift accumulated chunk moments (tiles left of t) through this tile's affine, add tile
    const float e = tD0, f = tC0;
    float nA  = gA + e * gP + A;
    float nL2 = gL2 + 2.f * e * gLP + e * e * gP2 + L2;
    float nLP = f * (gLP + e * gP2) + LP;
    float nP2 = f * f * gP2 + P2;
    float nP  = f * gP + Pp;
    gA = nA; gL2 = nL2; gLP = nLP; gP2 = nP2; gP = nP;
    // chunk affine K = K ∘ A_t
    float nKD = KD + KC * tD0;
    KC = KC * tC0; KD = nKD;
}

// Pass 1: per-chunk desc + moments + mask + fp16 delta, 2-deep pipelined.
__global__ __launch_bounds__(NT) void k_desc(const float* __restrict__ r,
                                             const float* __restrict__ v,
                                             const int* __restrict__ dn,
                                             float2* __restrict__ desc,
                                             float4* __restrict__ mom4,
                                             float* __restrict__ mom1,
                                             unsigned long long* __restrict__ dmask,
                                             __half* __restrict__ dh) {
    const int tid = threadIdx.x, lane = tid & 63, wv = tid >> 6;
    const int ch = blockIdx.x * 4 + wv;
    const int base = ch * CHUNK;
    float KD = 0.f, KC = 1.f, gA = 0.f, gP = 0.f, gL2 = 0.f, gLP = 0.f, gP2 = 0.f;
    TR ta, tb;
    load_tile(r, v, dn, base + 0 * TILE, lane, ta);
    load_tile(r, v, dn, base + 1 * TILE, lane, tb);
    process_tile(ta, lane, ch, 0, dh, dmask, base + 0 * TILE, KD, KC, gA, gP, gL2, gLP, gP2);
    load_tile(r, v, dn, base + 2 * TILE, lane, ta);
    process_tile(tb, lane, ch, 1, dh, dmask, base + 1 * TILE, KD, KC, gA, gP, gL2, gLP, gP2);
    load_tile(r, v, dn, base + 3 * TILE, lane, tb);
    process_tile(ta, lane, ch, 2, dh, dmask, base + 2 * TILE, KD, KC, gA, gP, gL2, gLP, gP2);
    process_tile(tb, lane, ch, 3, dh, dmask, base + 3 * TILE, KD, KC, gA, gP, gL2, gLP, gP2);
    // butterfly reduce the 5 chunk moments
#pragma unroll
    for (int off = 32; off > 0; off >>= 1) {
        gA  += __shfl_down(gA,  off);
        gP  += __shfl_down(gP,  off);
        gL2 += __shfl_down(gL2, off);
        gLP += __shfl_down(gLP, off);
        gP2 += __shfl_down(gP2, off);
    }
    if (lane == 0) {
        desc[ch] = make_float2(KD, KC);
        mom4[ch] = make_float4(gA, gP, gL2, gLP);
        mom1[ch] = gP2;
    }
}

// Pass 2: scan 16384 chunk descs -> carries; combine moments -> mean, 1/(std+eps).
// Shuffle-based scan, 2 barriers total.
__global__ __launch_bounds__(K2T) void k_scan(const float2* __restrict__ desc,
                                              const float4* __restrict__ mom4,
                                              const float* __restrict__ mom1,
                                              float* __restrict__ carry,
                                              float2* __restrict__ meanstd,
                                              int nchunk, long long T) {
    const int t = threadIdx.x, lane = t & 63, wv = t >> 6;   // 16 waves
    const int per = nchunk / K2T;   // 16
    const int s = t * per;
    float D = 0.f, C = 1.f;
    for (int i = per - 1; i >= 0; --i) { float2 a = desc[s + i]; D = a.x + a.y * D; C *= a.y; }
    // wave suffix scan of thread totals
    float sD = D, sC = C;
#pragma unroll
    for (int off = 1; off < 64; off <<= 1) {
        float tD = __shfl_down(sD, off), tC = __shfl_down(sC, off);
        if (lane + off < 64) { sD = sD + sC * tD; sC = sC * tC; }
    }
    __shared__ float2 waff[16];
    if (lane == 0) waff[wv] = make_float2(sD, sC);
    __syncthreads();
    float xw = 0.f;                              // value entering this wave from the right
    for (int w = 15; w > wv; --w) xw = waff[w].x + waff[w].y * xw;
    float S1D = __shfl_down(sD, 1), S1C = __shfl_down(sC, 1);
    if (lane == 63) { S1D = 0.f; S1C = 1.f; }
    float x = S1D + S1C * xw;                    // value entering this thread's range
    double gS = 0.0, gQ = 0.0;
    for (int i = per - 1; i >= 0; --i) {
        const int cix = s + i;
        carry[cix] = x;
        float4 m = mom4[cix];
        float p2 = mom1[cix];
        gS += (double)(m.x + x * m.y);
        gQ += (double)(m.z + 2.f * x * m.w + x * x * p2);
        float2 a = desc[cix];
        x = a.x + a.y * x;
    }
#pragma unroll
    for (int off = 32; off > 0; off >>= 1) {
        gS += __shfl_down(gS, off);
        gQ += __shfl_down(gQ, off);
    }
    __shared__ double Sa[16], Sb[16];
    if (lane == 0) { Sa[wv] = gS; Sb[wv] = gQ; }
    __syncthreads();
    if (t == 0) {
        double S = 0.0, Q = 0.0;
        for (int w = 0; w < 16; ++w) { S += Sa[w]; Q += Sb[w]; }
        double mean = S / (double)T;
        double var = Q / (double)T - mean * mean;
        double sd = sqrt(var > 0.0 ? var : 0.0);
        meanstd[0] = make_float2((float)mean, (float)(1.0 / (sd + (double)EPS_F)));
    }
}

// Pass 3: read fp16 delta + mask (L3-hot), rescan, apply carry, normalize, write out.
__global__ __launch_bounds__(NT) void k_apply(const __half* __restrict__ dh,
                                              const unsigned long long* __restrict__ dmask,
                                              const float* __restrict__ carry,
                                              const float2* __restrict__ meanstd,
                                              float* __restrict__ out) {
    const int tid = threadIdx.x, lane = tid & 63, wv = tid >> 6;
    const int ch = blockIdx.x * 4 + wv;
    const int base = ch * CHUNK;
    H4 u[4];
#pragma unroll
    for (int t = 0; t < 4; ++t) u[t].u2 = *(const uint2*)(dh + base + t * TILE + lane * 4);
    const unsigned long long* mp = dmask + (size_t)ch * 16;
    const float2 ms = *meanstd;
    float x = carry[ch];                         // value entering chunk from the right
#pragma unroll
    for (int t = 3; t >= 0; --t) {
        float d[4], c[4];
#pragma unroll
        for (int i = 0; i < 4; ++i) {
            d[i] = __half2float(u[t].h[i]);
            c[i] = GL_F * (1.f - (float)((mp[t * 4 + i] >> lane) & 1ull));
        }
        float D = 0.f, C = 1.f;
#pragma unroll
        for (int i = 3; i >= 0; --i) { D = d[i] + c[i] * D; C *= c[i]; }
#pragma unroll
        for (int off = 1; off < 64; off <<= 1) {
            float tD = __shfl_down(D, off), tC = __shfl_down(C, off);
            if (lane + off < 64) { D = D + C * tD; C = C * tC; }
        }
        float S1D = __shfl_down(D, 1), S1C = __shfl_down(C, 1);
        if (lane == 63) { S1D = 0.f; S1C = 1.f; }
        const float tD0 = __shfl(D, 0), tC0 = __shfl(C, 0);
        float xi = S1D + S1C * x;
        float o[4];
#pragma unroll
        for (int i = 3; i >= 0; --i) { xi = d[i] + c[i] * xi; o[i] = (xi - ms.x) * ms.y; }
        *(float4*)(out + base + t * TILE + lane * 4) = make_float4(o[0], o[1], o[2], o[3]);
        x = tD0 + tC0 * x;                       // advance entry to left edge of tile t
    }
}

extern "C" void kernel_launch(void* const* d_in, const int* in_sizes, int n_in,
                              void* d_out, int out_size, void* d_ws, size_t ws_size,
                              hipStream_t stream) {
    const float* rewards = (const float*)d_in[0];
    const float* v_pred  = (const float*)d_in[1];
    const int*   dones   = (const int*)d_in[2];
    float* out = (float*)d_out;
    const long long T = in_sizes[0];          // 16777216
    const int nchunk = (int)(T / CHUNK);      // 16384

    char* ws = (char*)d_ws;
    float4* mom4 = (float4*)ws;                                       // 256 KB @ 0
    float2* desc = (float2*)(ws + (size_t)nchunk * 16);               // 128 KB
    float*  mom1 = (float*)(ws + (size_t)nchunk * 24);                // 64 KB
    float*  carry = (float*)(ws + (size_t)nchunk * 28);               // 64 KB
    float2* meanstd = (float2*)(ws + (size_t)nchunk * 32);            // 16 B
    unsigned long long* dmask =
        (unsigned long long*)(ws + (size_t)nchunk * 32 + 16);         // 2 MB
    __half* dh = (__half*)(ws + 4ull * 1024 * 1024);                  // 32 MB @ 4 MB
    // ws_size >= 36 MB proven in R6 (half path executed: absmax 0.03125, WRITE 35.5 MB)

    hipLaunchKernelGGL(k_desc, dim3(nchunk / 4), dim3(NT), 0, stream,
                       rewards, v_pred, dones, desc, mom4, mom1, dmask, dh);
    hipLaunchKernelGGL(k_scan, dim3(1), dim3(K2T), 0, stream,
                       desc, mom4, mom1, carry, meanstd, nchunk, T);
    hipLaunchKernelGGL(k_apply, dim3(nchunk / 4), dim3(NT), 0, stream,
                       dh, dmask, carry, meanstd, out);
}

// Round 9
// 107.754 us; speedup vs baseline: 1.1365x; 1.1365x over previous
//
#include <hip/hip_runtime.h>
#include <hip/hip_fp16.h>

// GAE reverse affine scan + standardize — consolidated best-proven 3-kernel version.
// adv_k = delta_k + c_k*adv_{k+1}; delta_k = r_k + g*V_{k+1}*nd_k - V_k; c_k = g*l*nd_k.
// Affine f(x)=D+C*x; compose(left,right) = (Dl+Cl*Dr, Cl*Cr).
// Wave owns a 1024-elem chunk (2 tiles of 512; lane owns 8 contiguous elems).
// k_desc: stream r,v,dn once; persist fp16 delta (32 MB) + done bitmask (2 MB) +
//         per-chunk affine desc + 5-moment tuple. (R6-proven codegen: 40 VGPR, 0 LDS.)
// k_scan: single block, shuffle-based scan of 16384 descs -> carries + mean/std. (R7-proven.)
// k_apply: read fp16 delta + mask (L3-hot), rescan, apply carry, normalize, write out.

#define GAMMA_F 0.99f
#define GL_F 0.9405f            // 0.99*0.95
#define EPS_F 1e-8f

constexpr int NT = 256;          // 4 waves per block
constexpr int PL = 8;            // elems per lane
constexpr int TILE = 512;        // elems per wave-tile (64*8)
constexpr int CHUNK = 2 * TILE;  // 1024 elems per wave-chunk
constexpr int K2T = 1024;        // k_scan threads

union H8 { __half h[8]; float4 f4; };

// Suffix scan of 8 per-lane affines across the wave.
// sD,sC = A_lane∘...∘A_63 ; S1D,S1C = exclusive (identity at lane 63).
__device__ __forceinline__ void scan8(const float* d, const float* c, int lane,
                                      float& sD, float& sC, float& S1D, float& S1C) {
    float D = 0.f, C = 1.f;
#pragma unroll
    for (int i = 7; i >= 0; --i) { D = d[i] + c[i] * D; C *= c[i]; }
#pragma unroll
    for (int off = 1; off < 64; off <<= 1) {
        float tD = __shfl_down(D, off);
        float tC = __shfl_down(C, off);
        if (lane + off < 64) { D = D + C * tD; C = C * tC; }
    }
    sD = D; sC = C;
    S1D = __shfl_down(D, 1); S1C = __shfl_down(C, 1);
    if (lane == 63) { S1D = 0.f; S1C = 1.f; }
}

// delta/cont for one 512-elem tile from raw inputs, then scan.
__device__ __forceinline__ void tile_scan(const float4& r0, const float4& r1,
                                          const float4& v0, const float4& v1,
                                          const float* nd, float vn63, int lane,
                                          float* d, float* c,
                                          float& sD, float& sC, float& S1D, float& S1C) {
    float vnext = __shfl_down(v0.x, 1);
    if (lane == 63) vnext = vn63;
    float va[9] = {v0.x, v0.y, v0.z, v0.w, v1.x, v1.y, v1.z, v1.w, vnext};
    float rf[8] = {r0.x, r0.y, r0.z, r0.w, r1.x, r1.y, r1.z, r1.w};
#pragma unroll
    for (int i = 0; i < 8; ++i) {
        d[i] = rf[i] + GAMMA_F * va[i + 1] * nd[i] - va[i];
        c[i] = GL_F * nd[i];
    }
    scan8(d, c, lane, sD, sC, S1D, S1C);
}

// Per-lane tile-local moments (entry 0 at tile right edge): {Σloc, ΣP, Σloc², Σloc·P, ΣP²}.
__device__ __forceinline__ void lane_moms(const float* d, const float* c,
                                          float S1D, float S1C, float* mm) {
    float x = S1D, P = S1C;
    float A = 0.f, Pp = 0.f, L2 = 0.f, LP = 0.f, P2 = 0.f;
#pragma unroll
    for (int i = 7; i >= 0; --i) {
        x = d[i] + c[i] * x;
        P *= c[i];
        A += x; Pp += P; L2 += x * x; LP += x * P; P2 += P * P;
    }
    mm[0] = A; mm[1] = Pp; mm[2] = L2; mm[3] = LP; mm[4] = P2;
}

// Pass 1: per-chunk desc + moments + done-mask + persisted fp16 delta.
__global__ __launch_bounds__(NT) void k_desc(const float* __restrict__ r,
                                             const float* __restrict__ v,
                                             const int* __restrict__ dn,
                                             float2* __restrict__ desc,
                                             float4* __restrict__ mom4,
                                             float* __restrict__ mom1,
                                             unsigned long long* __restrict__ dmask,
                                             __half* __restrict__ dh) {
    const int tid = threadIdx.x, lane = tid & 63, wv = tid >> 6;
    const int ch = blockIdx.x * 4 + wv;
    const int base = ch * CHUNK;
    const int o0 = base + lane * PL, o1 = base + TILE + lane * PL;

    float4 r00 = *(const float4*)(r + o0), r01 = *(const float4*)(r + o0 + 4);
    float4 v00 = *(const float4*)(v + o0), v01 = *(const float4*)(v + o0 + 4);
    int4   a00 = *(const int4*)(dn + o0),  a01 = *(const int4*)(dn + o0 + 4);
    float4 r10 = *(const float4*)(r + o1), r11 = *(const float4*)(r + o1 + 4);
    float4 v10 = *(const float4*)(v + o1), v11 = *(const float4*)(v + o1 + 4);
    int4   a10 = *(const int4*)(dn + o1),  a11 = *(const int4*)(dn + o1 + 4);

    float vn63_t1 = (lane == 63) ? v[base + CHUNK] : 0.f;   // v has T+1 elems
    float vn63_t0 = __shfl(v10.x, 0);

    int di0[8] = {a00.x, a00.y, a00.z, a00.w, a01.x, a01.y, a01.z, a01.w};
    int di1[8] = {a10.x, a10.y, a10.z, a10.w, a11.x, a11.y, a11.z, a11.w};
    float nd0[8], nd1[8];
    unsigned long long m0[8], m1[8];
#pragma unroll
    for (int i = 0; i < 8; ++i) {
        nd0[i] = 1.f - (float)di0[i]; m0[i] = __ballot(di0[i] != 0);
        nd1[i] = 1.f - (float)di1[i]; m1[i] = __ballot(di1[i] != 0);
    }

    float d1[8], c1[8], sD1, sC1, S1D1, S1C1;
    tile_scan(r10, r11, v10, v11, nd1, vn63_t1, lane, d1, c1, sD1, sC1, S1D1, S1C1);
    const float T1D = __shfl(sD1, 0), T1C = __shfl(sC1, 0);
    float d0[8], c0[8], sD0, sC0, S1D0, S1C0;
    tile_scan(r00, r01, v00, v01, nd0, vn63_t0, lane, d0, c0, sD0, sC0, S1D0, S1C0);
    const float T0D = __shfl(sD0, 0), T0C = __shfl(sC0, 0);

    // persist fp16 delta (coalesced 16B/lane)
    H8 u0, u1;
#pragma unroll
    for (int i = 0; i < 8; ++i) { u0.h[i] = __float2half(d0[i]); u1.h[i] = __float2half(d1[i]); }
    *(float4*)(dh + o0) = u0.f4;
    *(float4*)(dh + o1) = u1.f4;

    float mm1[5], mm0[5];
    lane_moms(d1, c1, S1D1, S1C1, mm1);
    lane_moms(d0, c0, S1D0, S1C0, mm0);
    const float e = T1D, f = T1C;   // lift tile0 moments through tile1's affine
    float gA  = mm1[0] + mm0[0] + e * mm0[1];
    float gP  = mm1[1] + f * mm0[1];
    float gL2 = mm1[2] + mm0[2] + 2.f * e * mm0[3] + e * e * mm0[4];
    float gLP = mm1[3] + f * (mm0[3] + e * mm0[4]);
    float gP2 = mm1[4] + f * f * mm0[4];
#pragma unroll
    for (int off = 32; off > 0; off >>= 1) {
        gA  += __shfl_down(gA,  off);
        gP  += __shfl_down(gP,  off);
        gL2 += __shfl_down(gL2, off);
        gLP += __shfl_down(gLP, off);
        gP2 += __shfl_down(gP2, off);
    }
    if (lane == 0) {
        desc[ch] = make_float2(T0D + T0C * T1D, T0C * T1C);
        mom4[ch] = make_float4(gA, gP, gL2, gLP);
        mom1[ch] = gP2;
        unsigned long long* mp = dmask + (size_t)ch * 16;
#pragma unroll
        for (int i = 0; i < 8; ++i) { mp[i] = m0[i]; mp[8 + i] = m1[i]; }
    }
}

// Pass 2: scan 16384 chunk descs -> carries; combine moments -> mean, 1/(std+eps).
// Shuffle-based, 2 barriers total. (R7-proven.)
__global__ __launch_bounds__(K2T) void k_scan(const float2* __restrict__ desc,
                                              const float4* __restrict__ mom4,
                                              const float* __restrict__ mom1,
                                              float* __restrict__ carry,
                                              float2* __restrict__ meanstd,
                                              int nchunk, long long T) {
    const int t = threadIdx.x, lane = t & 63, wv = t >> 6;   // 16 waves
    const int per = nchunk / K2T;   // 16
    const int s = t * per;
    float D = 0.f, C = 1.f;
    for (int i = per - 1; i >= 0; --i) { float2 a = desc[s + i]; D = a.x + a.y * D; C *= a.y; }
    float sD = D, sC = C;
#pragma unroll
    for (int off = 1; off < 64; off <<= 1) {
        float tD = __shfl_down(sD, off), tC = __shfl_down(sC, off);
        if (lane + off < 64) { sD = sD + sC * tD; sC = sC * tC; }
    }
    __shared__ float2 waff[16];
    if (lane == 0) waff[wv] = make_float2(sD, sC);
    __syncthreads();
    float xw = 0.f;                              // value entering this wave from the right
    for (int w = 15; w > wv; --w) xw = waff[w].x + waff[w].y * xw;
    float S1D = __shfl_down(sD, 1), S1C = __shfl_down(sC, 1);
    if (lane == 63) { S1D = 0.f; S1C = 1.f; }
    float x = S1D + S1C * xw;                    // value entering this thread's range
    double gS = 0.0, gQ = 0.0;
    for (int i = per - 1; i >= 0; --i) {
        const int cix = s + i;
        carry[cix] = x;
        float4 m = mom4[cix];
        float p2 = mom1[cix];
        gS += (double)(m.x + x * m.y);
        gQ += (double)(m.z + 2.f * x * m.w + x * x * p2);
        float2 a = desc[cix];
        x = a.x + a.y * x;
    }
#pragma unroll
    for (int off = 32; off > 0; off >>= 1) {
        gS += __shfl_down(gS, off);
        gQ += __shfl_down(gQ, off);
    }
    __shared__ double Sa[16], Sb[16];
    if (lane == 0) { Sa[wv] = gS; Sb[wv] = gQ; }
    __syncthreads();
    if (t == 0) {
        double S = 0.0, Q = 0.0;
        for (int w = 0; w < 16; ++w) { S += Sa[w]; Q += Sb[w]; }
        double mean = S / (double)T;
        double var = Q / (double)T - mean * mean;
        double sd = sqrt(var > 0.0 ? var : 0.0);
        meanstd[0] = make_float2((float)mean, (float)(1.0 / (sd + (double)EPS_F)));
    }
}

// Pass 3: read fp16 delta + mask (L3-hot), rescan, apply carry, normalize, write out.
__global__ __launch_bounds__(NT) void k_apply(const __half* __restrict__ dh,
                                              const unsigned long long* __restrict__ dmask,
                                              const float* __restrict__ carry,
                                              const float2* __restrict__ meanstd,
                                              float* __restrict__ out) {
    const int tid = threadIdx.x, lane = tid & 63, wv = tid >> 6;
    const int ch = blockIdx.x * 4 + wv;
    const int base = ch * CHUNK;
    const int o0 = base + lane * PL, o1 = base + TILE + lane * PL;

    float d0[8], d1[8];
    H8 u0, u1;
    u0.f4 = *(const float4*)(dh + o0);
    u1.f4 = *(const float4*)(dh + o1);
#pragma unroll
    for (int i = 0; i < 8; ++i) { d0[i] = __half2float(u0.h[i]); d1[i] = __half2float(u1.h[i]); }

    const unsigned long long* mp = dmask + (size_t)ch * 16;
    float c0[8], c1[8];
#pragma unroll
    for (int i = 0; i < 8; ++i) {
        c0[i] = GL_F * (1.f - (float)((mp[i] >> lane) & 1ull));
        c1[i] = GL_F * (1.f - (float)((mp[8 + i] >> lane) & 1ull));
    }
    const float2 ms = meanstd[0];
    const float cy = carry[ch];

    float sD1, sC1, S1D1, S1C1;
    scan8(d1, c1, lane, sD1, sC1, S1D1, S1C1);
    const float T1D = __shfl(sD1, 0), T1C = __shfl(sC1, 0);
    float sD0, sC0, S1D0, S1C0;
    scan8(d0, c0, lane, sD0, sC0, S1D0, S1C0);

    float o[8];
    float x = S1D1 + S1C1 * cy;                   // tile1: entry = cy at chunk right edge
#pragma unroll
    for (int i = 7; i >= 0; --i) { x = d1[i] + c1[i] * x; o[i] = (x - ms.x) * ms.y; }
    *(float4*)(out + o1)     = make_float4(o[0], o[1], o[2], o[3]);
    *(float4*)(out + o1 + 4) = make_float4(o[4], o[5], o[6], o[7]);
    const float x0e = T1D + T1C * cy;             // tile0: entry = A_tile1(cy)
    x = S1D0 + S1C0 * x0e;
#pragma unroll
    for (int i = 7; i >= 0; --i) { x = d0[i] + c0[i] * x; o[i] = (x - ms.x) * ms.y; }
    *(float4*)(out + o0)     = make_float4(o[0], o[1], o[2], o[3]);
    *(float4*)(out + o0 + 4) = make_float4(o[4], o[5], o[6], o[7]);
}

extern "C" void kernel_launch(void* const* d_in, const int* in_sizes, int n_in,
                              void* d_out, int out_size, void* d_ws, size_t ws_size,
                              hipStream_t stream) {
    const float* rewards = (const float*)d_in[0];
    const float* v_pred  = (const float*)d_in[1];
    const int*   dones   = (const int*)d_in[2];
    float* out = (float*)d_out;
    const long long T = in_sizes[0];          // 16777216
    const int nchunk = (int)(T / CHUNK);      // 16384

    // workspace layout (ws_size >= 36 MB proven in R6: half path executed)
    char* ws = (char*)d_ws;
    float4* mom4 = (float4*)ws;                                       // 256 KB
    float2* desc = (float2*)(ws + (size_t)nchunk * 16);               // 128 KB
    float*  mom1 = (float*)(ws + (size_t)nchunk * 24);                // 64 KB
    float*  carry = (float*)(ws + (size_t)nchunk * 28);               // 64 KB
    float2* meanstd = (float2*)(ws + (size_t)nchunk * 32);            // 16 B
    unsigned long long* dmask =
        (unsigned long long*)(ws + (size_t)nchunk * 32 + 16);         // 2 MB
    __half* dh = (__half*)(ws + 4ull * 1024 * 1024);                  // 32 MB @ 4 MB

    hipLaunchKernelGGL(k_desc, dim3(nchunk / 4), dim3(NT), 0, stream,
                       rewards, v_pred, dones, desc, mom4, mom1, dmask, dh);
    hipLaunchKernelGGL(k_scan, dim3(1), dim3(K2T), 0, stream,
                       desc, mom4, mom1, carry, meanstd, nchunk, T);
    hipLaunchKernelGGL(k_apply, dim3(nchunk / 4), dim3(NT), 0, stream,
                       dh, dmask, carry, meanstd, out);
}